// Round 18
// baseline (136.549 us; speedup 1.0000x reference)
//
#include <hip/hip_runtime.h>
#include <math.h>

#define B_ 16
#define N_ 8192
#define H_ 128
#define T_ 256   // TOK_MLP
#define C_ 512   // CH_MLP

typedef __bf16 bf16x8 __attribute__((ext_vector_type(8)));
typedef __bf16 bf16x4 __attribute__((ext_vector_type(4)));
typedef float f32x4 __attribute__((ext_vector_type(4)));

// tanh-form gelu: x * sigmoid(1.5957691(x + 0.044715 x^3)).
__device__ __forceinline__ float gelu_f(float x) {
    float p = fmaf(0.044715f * x * x, x, x);
    float e = __expf(-1.5957691216057308f * p);
    return x * __builtin_amdgcn_rcpf(1.f + e);
}

__device__ __forceinline__ unsigned short f2bf(float x) {
    unsigned int u = __float_as_uint(x);
    u = (u + 0x7FFFu + ((u >> 16) & 1u)) >> 16;
    return (unsigned short)u;
}

__device__ __forceinline__ void gl2lds16(const void* g, void* l) {
    __builtin_amdgcn_global_load_lds(
        (const __attribute__((address_space(1))) void*)g,
        (__attribute__((address_space(3))) void*)l,
        16, 0, 0);
}

// w1ct row t (16KB): per 64-n chunk c: byte = (t*16384) + c*128 + ((nl*2) ^ ((t&7)<<4))
// Each block re-derives its own scan offset from psum[t][0..c) (contiguous per thread).
__global__ void k_w1_prefix(const float* __restrict__ w1, const float* __restrict__ psum,
                            unsigned short* __restrict__ w1ct) {
    int c = blockIdx.x, t = threadIdx.x;     // c: n-chunk 0..127
    const float* pp = psum + t * 128;
    float run = 0.f;
    for (int i = 0; i < c; ++i) run += pp[i];
    const float* p = w1 + (size_t)c * 64 * T_ + t;
    unsigned int wb[32];
    #pragma unroll
    for (int q = 0; q < 32; ++q) {
        run += p[(size_t)(2 * q) * T_];
        unsigned int lo = f2bf(run);
        run += p[(size_t)(2 * q + 1) * T_];
        wb[q] = lo | ((unsigned int)f2bf(run) << 16);
    }
    char* row = (char*)w1ct + ((size_t)t * N_ + c * 64) * 2;
    int key = (t & 7) << 4;
    #pragma unroll
    for (int pc = 0; pc < 8; ++pc) {
        int4 v = { (int)wb[4*pc], (int)wb[4*pc+1], (int)wb[4*pc+2], (int)wb[4*pc+3] };
        *(int4*)(row + ((pc * 16) ^ key)) = v;
    }
}

// ---------------- merged: tok_w2 transpose pack + ch-weight prepack + w1 psum ----------------
__global__ void k_packs(const float* __restrict__ w2, unsigned short* __restrict__ w2t,
                        const float* __restrict__ cw1, const float* __restrict__ cw2,
                        unsigned short* __restrict__ w1p, unsigned short* __restrict__ w2p,
                        const float* __restrict__ w1tok, float* __restrict__ psum) {
    __shared__ float ld[64 * 68];
    int tid = threadIdx.x;
    if (blockIdx.y < 4) {
        int nt = blockIdx.x, tt = blockIdx.y;   // 128 n-tiles x 4 t-tiles (64x64)
        int n0 = nt * 64, t0 = tt * 64;
        #pragma unroll
        for (int rnd = 0; rnd < 4; ++rnd) {
            int idx = tid + rnd * 256;
            int tr = idx >> 4, nc = idx & 15;
            float4 v = *(const float4*)(w2 + (size_t)(t0 + tr) * N_ + n0 + nc * 4);
            *(float4*)&ld[tr * 68 + nc * 4] = v;
        }
        __syncthreads();
        int n = tid >> 2, q = tid & 3;
        int key = (n & 7) << 4;
        unsigned int wb[8];
        #pragma unroll
        for (int j = 0; j < 8; ++j) {
            float a = ld[(q * 16 + 2 * j) * 68 + n];
            float b = ld[(q * 16 + 2 * j + 1) * 68 + n];
            wb[j] = (unsigned int)f2bf(a) | ((unsigned int)f2bf(b) << 16);
        }
        char* row = (char*)w2t + (size_t)(n0 + n) * 512 + t0 * 2;
        int4 v0 = { (int)wb[0], (int)wb[1], (int)wb[2], (int)wb[3] };
        int4 v1 = { (int)wb[4], (int)wb[5], (int)wb[6], (int)wb[7] };
        *(int4*)(row + ((q * 32) ^ key)) = v0;
        *(int4*)(row + ((q * 32 + 16) ^ key)) = v1;
    } else if (blockIdx.y < 8) {
        int e = ((blockIdx.y - 4) * 128 + blockIdx.x) * 256 + tid;   // 0..131071
        if (e < 65536) {
            int c = e >> 13, t = e & 8191;
            int n = t >> 7, j = t & 127;
            int k = j ^ ((n & 7) << 3);
            int hid = c * 64 + n;
            w1p[e] = f2bf(cw1[(size_t)k * C_ + hid]);
        } else {
            int e2 = e - 65536;
            int c = e2 >> 13, t = e2 & 8191;
            int n = t >> 6, j = t & 63;
            int k = j ^ ((n & 7) << 3);
            w2p[e2] = f2bf(cw2[(size_t)(c * 64 + k) * H_ + n]);
        }
    } else {   // w1 column-chunk partial sums -> psum[t][128] (transposed)
        int c = blockIdx.x, t = tid;
        const float* p = w1tok + (size_t)c * 64 * T_ + t;
        float s = 0.f;
        #pragma unroll 8
        for (int r = 0; r < 64; ++r) s += p[(size_t)r * T_];
        psum[t * 128 + c] = s;
    }
}

// ---------------- FUSED token GEMM1: LN1 + transpose + bf16 MFMA, split-K 16 ----------------
// SEQUENTIAL ownership-per-barrier schedule:
//   per K-step: LNW -> B1 -> COLW -> B2 -> [STAGEW(s+1) || MFMA(s)] -> B3.
// LDS: ys 16K [0,16K) single | ws dbuf 2x32K [16K,80K) | lnb f32 64x132 [80K,113K).
#define T1_YS 0
#define T1_WS 16384
#define T1_LN 81920

__global__ __launch_bounds__(1024, 1)
void k_tok1(const float* __restrict__ x, const float* __restrict__ lg,
            const float* __restrict__ lb, const unsigned short* __restrict__ w1ct,
            float* __restrict__ P) {
    __shared__ __align__(16) char sm[115712];
    float* lnb = (float*)(sm + T1_LN);
    int kk = blockIdx.x, b = blockIdx.y;
    int tid = threadIdx.x;
    int w = tid >> 6, lane = tid & 63;
    int lr = lane & 15, lk = lane >> 4;
    int mg = w >> 2, ng = w & 3;           // wave tile: 32h x 64t
    const char* wbg = (const char*)w1ct;
    int kbase = kk * 512;

    int rI = tid >> 4, lI = tid & 15;      // LNW: row rI, 8 h at lI*8
    int hII = tid >> 3, segII = tid & 7;   // COLW: column hII, 16B seg segII
    const float* xbase = x + ((size_t)b * N_ + kbase) * H_;

    float4 g0 = *(const float4*)(lg + lI * 8);
    float4 g1 = *(const float4*)(lg + lI * 8 + 4);
    float4 c0 = *(const float4*)(lb + lI * 8);
    float4 c1 = *(const float4*)(lb + lI * 8 + 4);

    f32x4 acc[2][4];
    #pragma unroll
    for (int i = 0; i < 2; ++i)
        #pragma unroll
        for (int j = 0; j < 4; ++j) acc[i][j] = (f32x4){0.f, 0.f, 0.f, 0.f};

    float4 xa, xb;
    auto XLOAD = [&](int t) {
        const float* p = xbase + (size_t)(t * 64 + rI) * H_ + lI * 8;
        xa = *(const float4*)p;
        xb = *(const float4*)(p + 4);
    };
    auto LNW = [&]() {
        float s1 = xa.x + xa.y + xa.z + xa.w + xb.x + xb.y + xb.z + xb.w;
        float s2 = xa.x*xa.x + xa.y*xa.y + xa.z*xa.z + xa.w*xa.w
                 + xb.x*xb.x + xb.y*xb.y + xb.z*xb.z + xb.w*xb.w;
        #pragma unroll
        for (int off = 1; off < 16; off <<= 1) {
            s1 += __shfl_xor(s1, off);
            s2 += __shfl_xor(s2, off);
        }
        float mean = s1 * (1.f / 128.f);
        float rstd = rsqrtf(s2 * (1.f / 128.f) - mean * mean + 1e-5f);
        float4 o0, o1;
        o0.x = (xa.x - mean) * rstd * g0.x + c0.x;
        o0.y = (xa.y - mean) * rstd * g0.y + c0.y;
        o0.z = (xa.z - mean) * rstd * g0.z + c0.z;
        o0.w = (xa.w - mean) * rstd * g0.w + c0.w;
        o1.x = (xb.x - mean) * rstd * g1.x + c1.x;
        o1.y = (xb.y - mean) * rstd * g1.y + c1.y;
        o1.z = (xb.z - mean) * rstd * g1.z + c1.z;
        o1.w = (xb.w - mean) * rstd * g1.w + c1.w;
        *(float4*)&lnb[rI * 132 + lI * 8]     = o0;
        *(float4*)&lnb[rI * 132 + lI * 8 + 4] = o1;
    };
    auto COLW = [&]() {
        unsigned int d[4];
        #pragma unroll
        for (int j = 0; j < 4; ++j) {
            float a = lnb[(segII * 8 + 2 * j) * 132 + hII];
            float c = lnb[(segII * 8 + 2 * j + 1) * 132 + hII];
            d[j] = (unsigned int)f2bf(a) | ((unsigned int)f2bf(c) << 16);
        }
        int4 v = { (int)d[0], (int)d[1], (int)d[2], (int)d[3] };
        *(int4*)(sm + T1_YS + hII * 128 + ((segII * 16) ^ ((hII & 7) << 4))) = v;
    };
    auto STAGEW = [&](int s, char* buf) {
        int n0 = kbase + s * 64;
        #pragma unroll
        for (int rnd = 0; rnd < 2; ++rnd) {
            int idx = tid + rnd * 1024;
            int tr = idx >> 3, pp = idx & 7;
            gl2lds16(wbg + ((size_t)tr * N_ + n0) * 2 + pp * 16, buf + idx * 16);
        }
    };

    STAGEW(0, sm + T1_WS);
    XLOAD(0);

    for (int s = 0; s < 8; ++s) {
        LNW();
        if (s < 7) XLOAD(s + 1);
        __syncthreads();             // B1: lnb ready
        COLW();
        __syncthreads();             // B2: ys ready
        if (s < 7) STAGEW(s + 1, sm + T1_WS + ((s + 1) & 1) * 32768);
        const char* wsb = sm + T1_WS + (s & 1) * 32768;
        #pragma unroll
        for (int ks = 0; ks < 2; ++ks) {
            bf16x8 af[2], bfr[4];
            #pragma unroll
            for (int i = 0; i < 2; ++i) {
                int h = mg * 32 + i * 16 + lr;
                af[i] = *(const bf16x8*)(sm + T1_YS + h * 128 + ((ks * 64 + lk * 16) ^ ((h & 7) << 4)));
            }
            #pragma unroll
            for (int j = 0; j < 4; ++j) {
                int t = ng * 64 + j * 16 + lr;
                bfr[j] = *(const bf16x8*)(wsb + t * 128 + ((ks * 64 + lk * 16) ^ ((t & 7) << 4)));
            }
            #pragma unroll
            for (int i = 0; i < 2; ++i)
                #pragma unroll
                for (int j = 0; j < 4; ++j)
                    acc[i][j] = __builtin_amdgcn_mfma_f32_16x16x32_bf16(af[i], bfr[j], acc[i][j], 0, 0, 0);
        }
        __syncthreads();             // B3
    }

    float* Pb = P + ((size_t)(b * 16 + kk)) * (H_ * T_);
    #pragma unroll
    for (int i = 0; i < 2; ++i)
        #pragma unroll
        for (int j = 0; j < 4; ++j) {
            int t = ng * 64 + j * 16 + lr;
            #pragma unroll
            for (int r = 0; r < 4; ++r) {
                int h = mg * 32 + i * 16 + lk * 4 + r;
                Pb[h * T_ + t] = acc[i][j][r];
            }
        }
}

// ---------------- combine partials + bias + gelu -> g1b bf16 [b][h][t] swizzled ----------------
__global__ void k_tok1_fin(const float* __restrict__ P, const float* __restrict__ b1,
                           unsigned short* __restrict__ g1b) {
    int fid = blockIdx.x * 256 + threadIdx.x;
    int base = fid * 4;
    int b = base >> 15, rem = base & 32767;
    int h = rem >> 8, t = rem & 255;
    const float* Pb = P + (size_t)b * 16 * 32768 + rem;
    float4 a = *(const float4*)Pb;
    #pragma unroll
    for (int kk = 1; kk < 16; ++kk) {
        float4 p = *(const float4*)(Pb + (size_t)kk * 32768);
        a.x += p.x; a.y += p.y; a.z += p.z; a.w += p.w;
    }
    float4 bb = *(const float4*)(b1 + t);
    unsigned int lo = (unsigned int)f2bf(gelu_f(a.x + bb.x)) | ((unsigned int)f2bf(gelu_f(a.y + bb.y)) << 16);
    unsigned int hi = (unsigned int)f2bf(gelu_f(a.z + bb.z)) | ((unsigned int)f2bf(gelu_f(a.w + bb.w)) << 16);
    char* row = (char*)g1b + (size_t)(b * H_ + h) * 512;
    uint2 v = { lo, hi };
    *(uint2*)(row + ((t * 2) ^ ((h & 7) << 4))) = v;
}

// ---------------- FUSED: token GEMM2 + tok_b2 + LN2 + channel MLP ----------------
// Phase A: K=256, 4 quarters, 2-phase dbuf (anchor, unchanged). LDS 64KB -> 2 blocks/CU.
// Phase B NEW: W1/W2 fragments read DIRECTLY from global (256KB total, L2-resident;
//   staging them through LDS was pure overhead -- L2-fit rule). hs double-buffered in
//   the dead ys region -> exactly ONE barrier per chunk (8 vs 16), no gl2lds in phase B.
//   Race audit: gelu(c)->bar(c)->GEMM2(c) gives hs visibility; hs[c&1] rewrite at c+2
//   is WAR-protected by bar(c+1) (every wave finishes GEMM2(c) before bar(c+1)).
#define F_YS 0

__global__ __launch_bounds__(512, 4)
void k_tok2mlp(const unsigned short* __restrict__ g1b, const unsigned short* __restrict__ w2t,
               const float* __restrict__ tb2, const float* __restrict__ lg,
               const float* __restrict__ lb, const unsigned short* __restrict__ w1p,
               const unsigned short* __restrict__ w2p, const float* __restrict__ b1g,
               const float* __restrict__ b2g, float* __restrict__ out) {
    __shared__ __align__(16) char sm[65536];
    int nt = blockIdx.x, b = blockIdx.y;
    int tid = threadIdx.x;
    int w = tid >> 6, lane = tid & 63;
    int lr = lane & 15, lk = lane >> 4;
    const char* ab = (const char*)w2t + (size_t)(nt * 128) * 512;
    const char* gb = (const char*)g1b + (size_t)b * H_ * 512;
    const char* w1b = (const char*)w1p;
    const char* w2b = (const char*)w2p;

    // ---- Phase A: tok GEMM2, K=256, 4 quarters, 2-phase dbuf (16x16 anchor) ----
    f32x4 acc[8];
    #pragma unroll
    for (int g = 0; g < 8; ++g) acc[g] = (f32x4){0.f, 0.f, 0.f, 0.f};

    int arow = w * 16 + lr;
    int akey = (arow & 7) << 4;

    #pragma unroll
    for (int rnd = 0; rnd < 2; ++rnd) {
        int idx = tid + rnd * 512;
        int row = idx >> 3, p = idx & 7;
        gl2lds16(ab + (size_t)row * 512 + p * 16, sm + row * 128 + p * 16);
        gl2lds16(gb + (size_t)row * 512 + p * 16, sm + 16384 + row * 128 + p * 16);
    }
    __syncthreads();

    for (int q = 0; q < 4; ++q) {
        const char* cur = sm + (q & 1) * 32768;
        if (q < 3) {
            char* nxt = sm + ((q + 1) & 1) * 32768;
            #pragma unroll
            for (int rnd = 0; rnd < 2; ++rnd) {
                int idx = tid + rnd * 512;
                int row = idx >> 3, p = idx & 7;
                gl2lds16(ab + (size_t)row * 512 + (q + 1) * 128 + p * 16, nxt + row * 128 + p * 16);
                gl2lds16(gb + (size_t)row * 512 + (q + 1) * 128 + p * 16, nxt + 16384 + row * 128 + p * 16);
            }
        }
        __builtin_amdgcn_s_setprio(1);
        #pragma unroll
        for (int ks = 0; ks < 2; ++ks) {
            bf16x8 af = *(const bf16x8*)(cur + arow * 128 + ((ks * 64 + lk * 16) ^ akey));
            #pragma unroll
            for (int g = 0; g < 8; ++g) {
                int hrow = g * 16 + lr;
                bf16x8 bf_ = *(const bf16x8*)(cur + 16384 + hrow * 128 + ((ks * 64 + lk * 16) ^ ((hrow & 7) << 4)));
                acc[g] = __builtin_amdgcn_mfma_f32_16x16x32_bf16(af, bf_, acc[g], 0, 0, 0);
            }
        }
        __builtin_amdgcn_s_setprio(0);
        __syncthreads();
    }

    float gam[8], bet[8];
    #pragma unroll
    for (int g = 0; g < 8; ++g) { gam[g] = lg[g * 16 + lr]; bet[g] = lb[g * 16 + lr]; }

    // LN2 -> ys tile [0,32K): rows tok 256B, byte (h*2)^((tok&7)<<4)
    #pragma unroll
    for (int r = 0; r < 4; ++r) {
        int row = w * 16 + lk * 4 + r;
        float bias2 = tb2[nt * 128 + row];
        float vals[8];
        float s = 0.f, ss = 0.f;
        #pragma unroll
        for (int g = 0; g < 8; ++g) {
            float v = acc[g][r] + bias2;
            vals[g] = v; s += v; ss += v * v;
        }
        #pragma unroll
        for (int off = 8; off; off >>= 1) { s += __shfl_xor(s, off); ss += __shfl_xor(ss, off); }
        float mean = s * (1.f / 128.f);
        float rstd = rsqrtf(ss * (1.f / 128.f) - mean * mean + 1e-5f);
        int key = (row & 7) << 4;
        char* orow = sm + F_YS + row * 256;
        #pragma unroll
        for (int g = 0; g < 8; ++g) {
            float v = (vals[g] - mean) * rstd * gam[g] + bet[g];
            *(unsigned short*)(orow + (((g * 16 + lr) * 2) ^ key)) = f2bf(v);
        }
    }
    __syncthreads();   // ys visible

    // ---- Phase B: channel MLP, weights direct from L2, hs double-buffered ----
    int mg = w >> 1, ng = w & 1;
    int key = (lr & 7) << 4;

    bf16x8 yfrag[2][4];
    #pragma unroll
    for (int m = 0; m < 2; ++m) {
        int yrow = (2 * mg + m) * 16 + lr;
        #pragma unroll
        for (int kc = 0; kc < 4; ++kc)
            yfrag[m][kc] = *(const bf16x8*)(sm + F_YS + yrow * 256 + ((kc * 64 + lk * 16) ^ key));
    }
    __syncthreads();   // ys fully consumed -> hs dbuf overlays [0,32K)

    f32x4 oacc[2][4];
    #pragma unroll
    for (int m = 0; m < 2; ++m)
        #pragma unroll
        for (int n = 0; n < 4; ++n) oacc[m][n] = (f32x4){0.f, 0.f, 0.f, 0.f};

    for (int c = 0; c < 8; ++c) {
        char* hsb = sm + (c & 1) * 16384;
        const char* w1c = w1b + c * 16384;
        const char* w2c = w2b + c * 16384;
        // GEMM1 (swapped): W1 fragments straight from global (L2-hot)
        f32x4 hacc[2][2];
        #pragma unroll
        for (int n = 0; n < 2; ++n) {
            float4 bv4 = *(const float4*)(b1g + c * 64 + (2 * ng + n) * 16 + lk * 4);
            f32x4 iv = { bv4.x, bv4.y, bv4.z, bv4.w };
            hacc[0][n] = iv;
            hacc[1][n] = iv;
        }
        __builtin_amdgcn_s_setprio(1);
        #pragma unroll
        for (int kc = 0; kc < 4; ++kc) {
            int ko = kc * 64 + lk * 16;
            bf16x8 b0 = *(const bf16x8*)(w1c + ((2 * ng) * 16 + lr) * 256 + (ko ^ key));
            bf16x8 b1 = *(const bf16x8*)(w1c + ((2 * ng + 1) * 16 + lr) * 256 + (ko ^ key));
            hacc[0][0] = __builtin_amdgcn_mfma_f32_16x16x32_bf16(b0, yfrag[0][kc], hacc[0][0], 0, 0, 0);
            hacc[0][1] = __builtin_amdgcn_mfma_f32_16x16x32_bf16(b1, yfrag[0][kc], hacc[0][1], 0, 0, 0);
            hacc[1][0] = __builtin_amdgcn_mfma_f32_16x16x32_bf16(b0, yfrag[1][kc], hacc[1][0], 0, 0, 0);
            hacc[1][1] = __builtin_amdgcn_mfma_f32_16x16x32_bf16(b1, yfrag[1][kc], hacc[1][1], 0, 0, 0);
        }
        __builtin_amdgcn_s_setprio(0);
        // gelu -> hs[c&1]: 128B rows, XOR swizzle
        #pragma unroll
        for (int m = 0; m < 2; ++m)
            #pragma unroll
            for (int n = 0; n < 2; ++n) {
                int tok = (2 * mg + m) * 16 + lr;
                int hid0 = (2 * ng + n) * 16 + lk * 4;
                bf16x4 pv;
                pv[0] = (__bf16)gelu_f(hacc[m][n][0]);
                pv[1] = (__bf16)gelu_f(hacc[m][n][1]);
                pv[2] = (__bf16)gelu_f(hacc[m][n][2]);
                pv[3] = (__bf16)gelu_f(hacc[m][n][3]);
                *(bf16x4*)(hsb + tok * 128 + ((hid0 * 2) ^ ((tok & 7) << 4))) = pv;
            }
        __syncthreads();   // hs[c&1] visible; also WAR-protects hs[(c+1)&1] rewrite
        // GEMM2: W2 fragments straight from global (L2-hot)
        __builtin_amdgcn_s_setprio(1);
        #pragma unroll
        for (int kc = 0; kc < 2; ++kc) {
            int ko = kc * 64 + lk * 16;
            int t0 = (2 * mg) * 16 + lr, t1 = (2 * mg + 1) * 16 + lr;
            bf16x8 a0 = *(const bf16x8*)(hsb + t0 * 128 + (ko ^ ((t0 & 7) << 4)));
            bf16x8 a1 = *(const bf16x8*)(hsb + t1 * 128 + (ko ^ ((t1 & 7) << 4)));
            #pragma unroll
            for (int n = 0; n < 4; ++n) {
                bf16x8 bb = *(const bf16x8*)(w2c + ((ng * 4 + n) * 16 + lr) * 128 + (ko ^ key));
                oacc[0][n] = __builtin_amdgcn_mfma_f32_16x16x32_bf16(a0, bb, oacc[0][n], 0, 0, 0);
                oacc[1][n] = __builtin_amdgcn_mfma_f32_16x16x32_bf16(a1, bb, oacc[1][n], 0, 0, 0);
            }
        }
        __builtin_amdgcn_s_setprio(0);
        // no second barrier: next chunk writes hs[(c+1)&1], reads no LDS until then
    }

    // epilogue: + ch_b2, f32 store
    size_t rbase = (size_t)(b * 64 + nt) * 128;
    #pragma unroll
    for (int n = 0; n < 4; ++n) {
        int ch = (ng * 4 + n) * 16 + lr;
        float bv = b2g[ch];
        #pragma unroll
        for (int m = 0; m < 2; ++m)
            #pragma unroll
            for (int r = 0; r < 4; ++r) {
                size_t row = rbase + (2 * mg + m) * 16 + lk * 4 + r;
                out[row * H_ + ch] = oacc[m][n][r] + bv;
            }
    }
}

extern "C" void kernel_launch(void* const* d_in, const int* in_sizes, int n_in,
                              void* d_out, int out_size, void* d_ws, size_t ws_size,
                              hipStream_t stream) {
    const float* x      = (const float*)d_in[0];
    const float* ln1_g  = (const float*)d_in[1];
    const float* ln1_b  = (const float*)d_in[2];
    const float* ln2_g  = (const float*)d_in[3];
    const float* ln2_b  = (const float*)d_in[4];
    const float* tok_w1 = (const float*)d_in[5];
    const float* tok_b1 = (const float*)d_in[6];
    const float* tok_w2 = (const float*)d_in[7];
    const float* tok_b2 = (const float*)d_in[8];
    const float* ch_w1  = (const float*)d_in[9];
    const float* ch_b1  = (const float*)d_in[10];
    const float* ch_w2  = (const float*)d_in[11];
    const float* ch_b2  = (const float*)d_in[12];
    float* out = (float*)d_out;
    float* ws  = (float*)d_ws;

    float* psum = ws;                                         //    32,768 f  [t][128]
    unsigned short* w1ct = (unsigned short*)(ws + 65536);     // 2M bf16 (4 MB)
    unsigned short* w2t  = (unsigned short*)(ws + 1114112);   // 2M bf16 (4 MB)
    unsigned short* w1p  = (unsigned short*)(ws + 2162688);   // 64K bf16
    unsigned short* w2p  = (unsigned short*)(ws + 2195456);   // 64K bf16
    unsigned short* g1b  = (unsigned short*)(ws + 2228224);   // 512K bf16 (1 MB)
    float* P             = ws + 2490368;                      // 8M f32 (32 MB)

    k_packs<<<dim3(128, 9), dim3(256), 0, stream>>>(tok_w2, w2t, ch_w1, ch_w2, w1p, w2p,
                                                    tok_w1, psum);
    k_w1_prefix<<<dim3(128), dim3(256), 0, stream>>>(tok_w1, psum, w1ct);
    k_tok1<<<dim3(16, 16), dim3(1024), 0, stream>>>(x, ln1_g, ln1_b, w1ct, P);
    k_tok1_fin<<<dim3(512), dim3(256), 0, stream>>>(P, tok_b1, g1b);
    k_tok2mlp<<<dim3(64, 16), dim3(512), 0, stream>>>(g1b, w2t, tok_b2, ln2_g, ln2_b,
                                                      w1p, w2p, ch_b1, ch_b2, out);
}

// Round 19
// 117.521 us; speedup vs baseline: 1.1619x; 1.1619x over previous
//
#include <hip/hip_runtime.h>
#include <math.h>

#define B_ 16
#define N_ 8192
#define H_ 128
#define T_ 256   // TOK_MLP
#define C_ 512   // CH_MLP

typedef __bf16 bf16x8 __attribute__((ext_vector_type(8)));
typedef __bf16 bf16x4 __attribute__((ext_vector_type(4)));
typedef float f32x4 __attribute__((ext_vector_type(4)));

// tanh-form gelu: x * sigmoid(1.5957691(x + 0.044715 x^3)).
__device__ __forceinline__ float gelu_f(float x) {
    float p = fmaf(0.044715f * x * x, x, x);
    float e = __expf(-1.5957691216057308f * p);
    return x * __builtin_amdgcn_rcpf(1.f + e);
}

__device__ __forceinline__ unsigned short f2bf(float x) {
    unsigned int u = __float_as_uint(x);
    u = (u + 0x7FFFu + ((u >> 16) & 1u)) >> 16;
    return (unsigned short)u;
}

__device__ __forceinline__ void gl2lds16(const void* g, void* l) {
    __builtin_amdgcn_global_load_lds(
        (const __attribute__((address_space(1))) void*)g,
        (__attribute__((address_space(3))) void*)l,
        16, 0, 0);
}

// scan over 128 chunks; psum is [t][128] (contiguous per thread -> pipelined loads)
__global__ void k_w1_scan(const float* __restrict__ psum, float* __restrict__ offs) {
    int t = threadIdx.x;
    const float* p = psum + t * 128;
    float run = 0.f;
    #pragma unroll 8
    for (int c = 0; c < 128; ++c) {
        offs[c * T_ + t] = run;
        run += p[c];
    }
}

// w1ct row t (16KB): per 64-n chunk c: byte = (t*16384) + c*128 + ((nl*2) ^ ((t&7)<<4))
__global__ void k_w1_prefix(const float* __restrict__ w1, const float* __restrict__ offs,
                            unsigned short* __restrict__ w1ct) {
    int c = blockIdx.x, t = threadIdx.x;     // c: n-chunk 0..127
    float run = offs[c * T_ + t];
    const float* p = w1 + (size_t)c * 64 * T_ + t;
    unsigned int wb[32];
    #pragma unroll
    for (int q = 0; q < 32; ++q) {
        run += p[(size_t)(2 * q) * T_];
        unsigned int lo = f2bf(run);
        run += p[(size_t)(2 * q + 1) * T_];
        wb[q] = lo | ((unsigned int)f2bf(run) << 16);
    }
    char* row = (char*)w1ct + ((size_t)t * N_ + c * 64) * 2;
    int key = (t & 7) << 4;
    #pragma unroll
    for (int pc = 0; pc < 8; ++pc) {
        int4 v = { (int)wb[4*pc], (int)wb[4*pc+1], (int)wb[4*pc+2], (int)wb[4*pc+3] };
        *(int4*)(row + ((pc * 16) ^ key)) = v;
    }
}

// ---------------- merged: tok_w2 transpose pack + ch-weight prepack + w1 psum ----------------
__global__ void k_packs(const float* __restrict__ w2, unsigned short* __restrict__ w2t,
                        const float* __restrict__ cw1, const float* __restrict__ cw2,
                        unsigned short* __restrict__ w1p, unsigned short* __restrict__ w2p,
                        const float* __restrict__ w1tok, float* __restrict__ psum) {
    __shared__ float ld[64 * 68];
    int tid = threadIdx.x;
    if (blockIdx.y < 4) {
        int nt = blockIdx.x, tt = blockIdx.y;   // 128 n-tiles x 4 t-tiles (64x64)
        int n0 = nt * 64, t0 = tt * 64;
        #pragma unroll
        for (int rnd = 0; rnd < 4; ++rnd) {
            int idx = tid + rnd * 256;
            int tr = idx >> 4, nc = idx & 15;
            float4 v = *(const float4*)(w2 + (size_t)(t0 + tr) * N_ + n0 + nc * 4);
            *(float4*)&ld[tr * 68 + nc * 4] = v;
        }
        __syncthreads();
        int n = tid >> 2, q = tid & 3;
        int key = (n & 7) << 4;
        unsigned int wb[8];
        #pragma unroll
        for (int j = 0; j < 8; ++j) {
            float a = ld[(q * 16 + 2 * j) * 68 + n];
            float b = ld[(q * 16 + 2 * j + 1) * 68 + n];
            wb[j] = (unsigned int)f2bf(a) | ((unsigned int)f2bf(b) << 16);
        }
        char* row = (char*)w2t + (size_t)(n0 + n) * 512 + t0 * 2;
        int4 v0 = { (int)wb[0], (int)wb[1], (int)wb[2], (int)wb[3] };
        int4 v1 = { (int)wb[4], (int)wb[5], (int)wb[6], (int)wb[7] };
        *(int4*)(row + ((q * 32) ^ key)) = v0;
        *(int4*)(row + ((q * 32 + 16) ^ key)) = v1;
    } else if (blockIdx.y < 8) {
        int e = ((blockIdx.y - 4) * 128 + blockIdx.x) * 256 + tid;   // 0..131071
        if (e < 65536) {
            int c = e >> 13, t = e & 8191;
            int n = t >> 7, j = t & 127;
            int k = j ^ ((n & 7) << 3);
            int hid = c * 64 + n;
            w1p[e] = f2bf(cw1[(size_t)k * C_ + hid]);
        } else {
            int e2 = e - 65536;
            int c = e2 >> 13, t = e2 & 8191;
            int n = t >> 6, j = t & 63;
            int k = j ^ ((n & 7) << 3);
            w2p[e2] = f2bf(cw2[(size_t)(c * 64 + k) * H_ + n]);
        }
    } else {   // w1 column-chunk partial sums -> psum[t][128] (transposed for the scan)
        int c = blockIdx.x, t = tid;
        const float* p = w1tok + (size_t)c * 64 * T_ + t;
        float s = 0.f;
        #pragma unroll 8
        for (int r = 0; r < 64; ++r) s += p[(size_t)r * T_];
        psum[t * 128 + c] = s;
    }
}

// ---------------- FUSED token GEMM1: LN1 + transpose + bf16 MFMA, split-K 16 ----------------
// SEQUENTIAL ownership-per-barrier schedule:
//   per K-step: LNW -> B1 -> COLW -> B2 -> [STAGEW(s+1) || MFMA(s)] -> B3.
// LDS: ys 16K [0,16K) single | ws dbuf 2x32K [16K,80K) | lnb f32 64x132 [80K,113K).
#define T1_YS 0
#define T1_WS 16384
#define T1_LN 81920

__global__ __launch_bounds__(1024, 1)
void k_tok1(const float* __restrict__ x, const float* __restrict__ lg,
            const float* __restrict__ lb, const unsigned short* __restrict__ w1ct,
            float* __restrict__ P) {
    __shared__ __align__(16) char sm[115712];
    float* lnb = (float*)(sm + T1_LN);
    int kk = blockIdx.x, b = blockIdx.y;
    int tid = threadIdx.x;
    int w = tid >> 6, lane = tid & 63;
    int lr = lane & 15, lk = lane >> 4;
    int mg = w >> 2, ng = w & 3;           // wave tile: 32h x 64t
    const char* wbg = (const char*)w1ct;
    int kbase = kk * 512;

    int rI = tid >> 4, lI = tid & 15;      // LNW: row rI, 8 h at lI*8
    int hII = tid >> 3, segII = tid & 7;   // COLW: column hII, 16B seg segII
    const float* xbase = x + ((size_t)b * N_ + kbase) * H_;

    float4 g0 = *(const float4*)(lg + lI * 8);
    float4 g1 = *(const float4*)(lg + lI * 8 + 4);
    float4 c0 = *(const float4*)(lb + lI * 8);
    float4 c1 = *(const float4*)(lb + lI * 8 + 4);

    f32x4 acc[2][4];
    #pragma unroll
    for (int i = 0; i < 2; ++i)
        #pragma unroll
        for (int j = 0; j < 4; ++j) acc[i][j] = (f32x4){0.f, 0.f, 0.f, 0.f};

    float4 xa, xb;
    auto XLOAD = [&](int t) {
        const float* p = xbase + (size_t)(t * 64 + rI) * H_ + lI * 8;
        xa = *(const float4*)p;
        xb = *(const float4*)(p + 4);
    };
    auto LNW = [&]() {
        float s1 = xa.x + xa.y + xa.z + xa.w + xb.x + xb.y + xb.z + xb.w;
        float s2 = xa.x*xa.x + xa.y*xa.y + xa.z*xa.z + xa.w*xa.w
                 + xb.x*xb.x + xb.y*xb.y + xb.z*xb.z + xb.w*xb.w;
        #pragma unroll
        for (int off = 1; off < 16; off <<= 1) {
            s1 += __shfl_xor(s1, off);
            s2 += __shfl_xor(s2, off);
        }
        float mean = s1 * (1.f / 128.f);
        float rstd = rsqrtf(s2 * (1.f / 128.f) - mean * mean + 1e-5f);
        float4 o0, o1;
        o0.x = (xa.x - mean) * rstd * g0.x + c0.x;
        o0.y = (xa.y - mean) * rstd * g0.y + c0.y;
        o0.z = (xa.z - mean) * rstd * g0.z + c0.z;
        o0.w = (xa.w - mean) * rstd * g0.w + c0.w;
        o1.x = (xb.x - mean) * rstd * g1.x + c1.x;
        o1.y = (xb.y - mean) * rstd * g1.y + c1.y;
        o1.z = (xb.z - mean) * rstd * g1.z + c1.z;
        o1.w = (xb.w - mean) * rstd * g1.w + c1.w;
        *(float4*)&lnb[rI * 132 + lI * 8]     = o0;
        *(float4*)&lnb[rI * 132 + lI * 8 + 4] = o1;
    };
    auto COLW = [&]() {
        unsigned int d[4];
        #pragma unroll
        for (int j = 0; j < 4; ++j) {
            float a = lnb[(segII * 8 + 2 * j) * 132 + hII];
            float c = lnb[(segII * 8 + 2 * j + 1) * 132 + hII];
            d[j] = (unsigned int)f2bf(a) | ((unsigned int)f2bf(c) << 16);
        }
        int4 v = { (int)d[0], (int)d[1], (int)d[2], (int)d[3] };
        *(int4*)(sm + T1_YS + hII * 128 + ((segII * 16) ^ ((hII & 7) << 4))) = v;
    };
    auto STAGEW = [&](int s, char* buf) {
        int n0 = kbase + s * 64;
        #pragma unroll
        for (int rnd = 0; rnd < 2; ++rnd) {
            int idx = tid + rnd * 1024;
            int tr = idx >> 3, pp = idx & 7;
            gl2lds16(wbg + ((size_t)tr * N_ + n0) * 2 + pp * 16, buf + idx * 16);
        }
    };

    STAGEW(0, sm + T1_WS);
    XLOAD(0);

    for (int s = 0; s < 8; ++s) {
        LNW();
        if (s < 7) XLOAD(s + 1);
        __syncthreads();             // B1: lnb ready
        COLW();
        __syncthreads();             // B2: ys ready
        if (s < 7) STAGEW(s + 1, sm + T1_WS + ((s + 1) & 1) * 32768);
        const char* wsb = sm + T1_WS + (s & 1) * 32768;
        #pragma unroll
        for (int ks = 0; ks < 2; ++ks) {
            bf16x8 af[2], bfr[4];
            #pragma unroll
            for (int i = 0; i < 2; ++i) {
                int h = mg * 32 + i * 16 + lr;
                af[i] = *(const bf16x8*)(sm + T1_YS + h * 128 + ((ks * 64 + lk * 16) ^ ((h & 7) << 4)));
            }
            #pragma unroll
            for (int j = 0; j < 4; ++j) {
                int t = ng * 64 + j * 16 + lr;
                bfr[j] = *(const bf16x8*)(wsb + t * 128 + ((ks * 64 + lk * 16) ^ ((t & 7) << 4)));
            }
            #pragma unroll
            for (int i = 0; i < 2; ++i)
                #pragma unroll
                for (int j = 0; j < 4; ++j)
                    acc[i][j] = __builtin_amdgcn_mfma_f32_16x16x32_bf16(af[i], bfr[j], acc[i][j], 0, 0, 0);
        }
        __syncthreads();             // B3
    }

    float* Pb = P + ((size_t)(b * 16 + kk)) * (H_ * T_);
    #pragma unroll
    for (int i = 0; i < 2; ++i)
        #pragma unroll
        for (int j = 0; j < 4; ++j) {
            int t = ng * 64 + j * 16 + lr;
            #pragma unroll
            for (int r = 0; r < 4; ++r) {
                int h = mg * 32 + i * 16 + lk * 4 + r;
                Pb[h * T_ + t] = acc[i][j][r];
            }
        }
}

// ---------------- combine partials + bias + gelu -> g1b bf16 [b][h][t] swizzled ----------------
__global__ void k_tok1_fin(const float* __restrict__ P, const float* __restrict__ b1,
                           unsigned short* __restrict__ g1b) {
    int fid = blockIdx.x * 256 + threadIdx.x;
    int base = fid * 4;
    int b = base >> 15, rem = base & 32767;
    int h = rem >> 8, t = rem & 255;
    const float* Pb = P + (size_t)b * 16 * 32768 + rem;
    float4 a = *(const float4*)Pb;
    #pragma unroll
    for (int kk = 1; kk < 16; ++kk) {
        float4 p = *(const float4*)(Pb + (size_t)kk * 32768);
        a.x += p.x; a.y += p.y; a.z += p.z; a.w += p.w;
    }
    float4 bb = *(const float4*)(b1 + t);
    unsigned int lo = (unsigned int)f2bf(gelu_f(a.x + bb.x)) | ((unsigned int)f2bf(gelu_f(a.y + bb.y)) << 16);
    unsigned int hi = (unsigned int)f2bf(gelu_f(a.z + bb.z)) | ((unsigned int)f2bf(gelu_f(a.w + bb.w)) << 16);
    char* row = (char*)g1b + (size_t)(b * H_ + h) * 512;
    uint2 v = { lo, hi };
    *(uint2*)(row + ((t * 2) ^ ((h & 7) << 4))) = v;
}

// ---------------- FUSED: token GEMM2 + tok_b2 + LN2 + channel MLP (verified anchor) ----------------
#define F_YS 0
#define F_HS 0
#define F_W2 32768
#define F_W1 49152

__global__ __launch_bounds__(512, 4)
void k_tok2mlp(const unsigned short* __restrict__ g1b, const unsigned short* __restrict__ w2t,
               const float* __restrict__ tb2, const float* __restrict__ lg,
               const float* __restrict__ lb, const unsigned short* __restrict__ w1p,
               const unsigned short* __restrict__ w2p, const float* __restrict__ b1g,
               const float* __restrict__ b2g, float* __restrict__ out) {
    __shared__ __align__(16) char sm[65536];
    int nt = blockIdx.x, b = blockIdx.y;
    int tid = threadIdx.x;
    int w = tid >> 6, lane = tid & 63;
    int lr = lane & 15, lk = lane >> 4;
    const char* ab = (const char*)w2t + (size_t)(nt * 128) * 512;
    const char* gb = (const char*)g1b + (size_t)b * H_ * 512;
    const char* w1b = (const char*)w1p;
    const char* w2b = (const char*)w2p;

    // ---- Phase A: tok GEMM2, K=256, 4 quarters, 2-phase dbuf (16x16 anchor) ----
    f32x4 acc[8];
    #pragma unroll
    for (int g = 0; g < 8; ++g) acc[g] = (f32x4){0.f, 0.f, 0.f, 0.f};

    int arow = w * 16 + lr;
    int akey = (arow & 7) << 4;

    #pragma unroll
    for (int rnd = 0; rnd < 2; ++rnd) {
        int idx = tid + rnd * 512;
        int row = idx >> 3, p = idx & 7;
        gl2lds16(ab + (size_t)row * 512 + p * 16, sm + row * 128 + p * 16);
        gl2lds16(gb + (size_t)row * 512 + p * 16, sm + 16384 + row * 128 + p * 16);
    }
    __syncthreads();

    for (int q = 0; q < 4; ++q) {
        const char* cur = sm + (q & 1) * 32768;
        if (q < 3) {
            char* nxt = sm + ((q + 1) & 1) * 32768;
            #pragma unroll
            for (int rnd = 0; rnd < 2; ++rnd) {
                int idx = tid + rnd * 512;
                int row = idx >> 3, p = idx & 7;
                gl2lds16(ab + (size_t)row * 512 + (q + 1) * 128 + p * 16, nxt + row * 128 + p * 16);
                gl2lds16(gb + (size_t)row * 512 + (q + 1) * 128 + p * 16, nxt + 16384 + row * 128 + p * 16);
            }
        }
        __builtin_amdgcn_s_setprio(1);
        #pragma unroll
        for (int ks = 0; ks < 2; ++ks) {
            bf16x8 af = *(const bf16x8*)(cur + arow * 128 + ((ks * 64 + lk * 16) ^ akey));
            #pragma unroll
            for (int g = 0; g < 8; ++g) {
                int hrow = g * 16 + lr;
                bf16x8 bf_ = *(const bf16x8*)(cur + 16384 + hrow * 128 + ((ks * 64 + lk * 16) ^ ((hrow & 7) << 4)));
                acc[g] = __builtin_amdgcn_mfma_f32_16x16x32_bf16(af, bf_, acc[g], 0, 0, 0);
            }
        }
        __builtin_amdgcn_s_setprio(0);
        __syncthreads();
    }

    float gam[8], bet[8];
    #pragma unroll
    for (int g = 0; g < 8; ++g) { gam[g] = lg[g * 16 + lr]; bet[g] = lb[g * 16 + lr]; }

    // prefetch chunk-0 weights, concurrent with LN2
    #pragma unroll
    for (int j = 0; j < 2; ++j) {
        gl2lds16(w1b + w * 2048 + j * 1024 + lane * 16, sm + F_W1 + w * 2048 + j * 1024);
        gl2lds16(w2b + w * 2048 + j * 1024 + lane * 16, sm + F_W2 + w * 2048 + j * 1024);
    }

    // LN2 -> ys tile [0,32K): rows tok 256B, byte (h*2)^((tok&7)<<4)
    #pragma unroll
    for (int r = 0; r < 4; ++r) {
        int row = w * 16 + lk * 4 + r;
        float bias2 = tb2[nt * 128 + row];
        float vals[8];
        float s = 0.f, ss = 0.f;
        #pragma unroll
        for (int g = 0; g < 8; ++g) {
            float v = acc[g][r] + bias2;
            vals[g] = v; s += v; ss += v * v;
        }
        #pragma unroll
        for (int off = 8; off; off >>= 1) { s += __shfl_xor(s, off); ss += __shfl_xor(ss, off); }
        float mean = s * (1.f / 128.f);
        float rstd = rsqrtf(ss * (1.f / 128.f) - mean * mean + 1e-5f);
        int key = (row & 7) << 4;
        char* orow = sm + F_YS + row * 256;
        #pragma unroll
        for (int g = 0; g < 8; ++g) {
            float v = (vals[g] - mean) * rstd * gam[g] + bet[g];
            *(unsigned short*)(orow + (((g * 16 + lr) * 2) ^ key)) = f2bf(v);
        }
    }
    __syncthreads();   // ys visible; W1(0)/W2(0) drained

    // ---- Phase B: channel MLP ----
    int mg = w >> 1, ng = w & 1;
    int key = (lr & 7) << 4;

    bf16x8 yfrag[2][4];
    #pragma unroll
    for (int m = 0; m < 2; ++m) {
        int yrow = (2 * mg + m) * 16 + lr;
        #pragma unroll
        for (int kc = 0; kc < 4; ++kc)
            yfrag[m][kc] = *(const bf16x8*)(sm + F_YS + yrow * 256 + ((kc * 64 + lk * 16) ^ key));
    }
    __syncthreads();   // ys fully consumed -> hs may overlay [0,16K)

    f32x4 oacc[2][4];
    #pragma unroll
    for (int m = 0; m < 2; ++m)
        #pragma unroll
        for (int n = 0; n < 4; ++n) oacc[m][n] = (f32x4){0.f, 0.f, 0.f, 0.f};

    for (int c = 0; c < 8; ++c) {
        f32x4 hacc[2][2];
        #pragma unroll
        for (int n = 0; n < 2; ++n) {
            float4 bv4 = *(const float4*)(b1g + c * 64 + (2 * ng + n) * 16 + lk * 4);
            f32x4 iv = { bv4.x, bv4.y, bv4.z, bv4.w };
            hacc[0][n] = iv;
            hacc[1][n] = iv;
        }
        __builtin_amdgcn_s_setprio(1);
        #pragma unroll
        for (int kc = 0; kc < 4; ++kc) {
            int ko = kc * 64 + lk * 16;
            bf16x8 b0 = *(const bf16x8*)(sm + F_W1 + ((2 * ng) * 16 + lr) * 256 + (ko ^ key));
            bf16x8 b1 = *(const bf16x8*)(sm + F_W1 + ((2 * ng + 1) * 16 + lr) * 256 + (ko ^ key));
            hacc[0][0] = __builtin_amdgcn_mfma_f32_16x16x32_bf16(b0, yfrag[0][kc], hacc[0][0], 0, 0, 0);
            hacc[0][1] = __builtin_amdgcn_mfma_f32_16x16x32_bf16(b1, yfrag[0][kc], hacc[0][1], 0, 0, 0);
            hacc[1][0] = __builtin_amdgcn_mfma_f32_16x16x32_bf16(b0, yfrag[1][kc], hacc[1][0], 0, 0, 0);
            hacc[1][1] = __builtin_amdgcn_mfma_f32_16x16x32_bf16(b1, yfrag[1][kc], hacc[1][1], 0, 0, 0);
        }
        __builtin_amdgcn_s_setprio(0);
        #pragma unroll
        for (int m = 0; m < 2; ++m)
            #pragma unroll
            for (int n = 0; n < 2; ++n) {
                int tok = (2 * mg + m) * 16 + lr;
                int hid0 = (2 * ng + n) * 16 + lk * 4;
                bf16x4 pv;
                pv[0] = (__bf16)gelu_f(hacc[m][n][0]);
                pv[1] = (__bf16)gelu_f(hacc[m][n][1]);
                pv[2] = (__bf16)gelu_f(hacc[m][n][2]);
                pv[3] = (__bf16)gelu_f(hacc[m][n][3]);
                *(bf16x4*)(sm + F_HS + tok * 128 + ((hid0 * 2) ^ ((tok & 7) << 4))) = pv;
            }
        __syncthreads();   // hs visible; W2(c) drained
        if (c < 7) {
            #pragma unroll
            for (int j = 0; j < 2; ++j)
                gl2lds16(w1b + (c + 1) * 16384 + w * 2048 + j * 1024 + lane * 16,
                         sm + F_W1 + w * 2048 + j * 1024);
        }
        __builtin_amdgcn_s_setprio(1);
        #pragma unroll
        for (int kc = 0; kc < 2; ++kc) {
            int ko = kc * 64 + lk * 16;
            int t0 = (2 * mg) * 16 + lr, t1 = (2 * mg + 1) * 16 + lr;
            bf16x8 a0 = *(const bf16x8*)(sm + F_HS + t0 * 128 + (ko ^ ((t0 & 7) << 4)));
            bf16x8 a1 = *(const bf16x8*)(sm + F_HS + t1 * 128 + (ko ^ ((t1 & 7) << 4)));
            #pragma unroll
            for (int n = 0; n < 4; ++n) {
                bf16x8 bb = *(const bf16x8*)(sm + F_W2 + ((ng * 4 + n) * 16 + lr) * 128 + (ko ^ key));
                oacc[0][n] = __builtin_amdgcn_mfma_f32_16x16x32_bf16(a0, bb, oacc[0][n], 0, 0, 0);
                oacc[1][n] = __builtin_amdgcn_mfma_f32_16x16x32_bf16(a1, bb, oacc[1][n], 0, 0, 0);
            }
        }
        __builtin_amdgcn_s_setprio(0);
        __syncthreads();   // W1(c+1) drained; hs dead
        if (c < 7) {
            #pragma unroll
            for (int j = 0; j < 2; ++j)
                gl2lds16(w2b + (c + 1) * 16384 + w * 2048 + j * 1024 + lane * 16,
                         sm + F_W2 + w * 2048 + j * 1024);
        }
    }

    // epilogue: + ch_b2, f32 store
    size_t rbase = (size_t)(b * 64 + nt) * 128;
    #pragma unroll
    for (int n = 0; n < 4; ++n) {
        int ch = (ng * 4 + n) * 16 + lr;
        float bv = b2g[ch];
        #pragma unroll
        for (int m = 0; m < 2; ++m)
            #pragma unroll
            for (int r = 0; r < 4; ++r) {
                size_t row = rbase + (2 * mg + m) * 16 + lk * 4 + r;
                out[row * H_ + ch] = oacc[m][n][r] + bv;
            }
    }
}

extern "C" void kernel_launch(void* const* d_in, const int* in_sizes, int n_in,
                              void* d_out, int out_size, void* d_ws, size_t ws_size,
                              hipStream_t stream) {
    const float* x      = (const float*)d_in[0];
    const float* ln1_g  = (const float*)d_in[1];
    const float* ln1_b  = (const float*)d_in[2];
    const float* ln2_g  = (const float*)d_in[3];
    const float* ln2_b  = (const float*)d_in[4];
    const float* tok_w1 = (const float*)d_in[5];
    const float* tok_b1 = (const float*)d_in[6];
    const float* tok_w2 = (const float*)d_in[7];
    const float* tok_b2 = (const float*)d_in[8];
    const float* ch_w1  = (const float*)d_in[9];
    const float* ch_b1  = (const float*)d_in[10];
    const float* ch_w2  = (const float*)d_in[11];
    const float* ch_b2  = (const float*)d_in[12];
    float* out = (float*)d_out;
    float* ws  = (float*)d_ws;

    float* psum = ws;                                         //    32,768 f  [t][128]
    float* offs = ws + 32768;                                 //    32,768 f
    unsigned short* w1ct = (unsigned short*)(ws + 65536);     // 2M bf16 (4 MB)
    unsigned short* w2t  = (unsigned short*)(ws + 1114112);   // 2M bf16 (4 MB)
    unsigned short* w1p  = (unsigned short*)(ws + 2162688);   // 64K bf16
    unsigned short* w2p  = (unsigned short*)(ws + 2195456);   // 64K bf16
    unsigned short* g1b  = (unsigned short*)(ws + 2228224);   // 512K bf16 (1 MB)
    float* P             = ws + 2490368;                      // 8M f32 (32 MB)

    k_packs<<<dim3(128, 9), dim3(256), 0, stream>>>(tok_w2, w2t, ch_w1, ch_w2, w1p, w2p,
                                                    tok_w1, psum);
    k_w1_scan<<<dim3(1), dim3(256), 0, stream>>>(psum, offs);
    k_w1_prefix<<<dim3(128), dim3(256), 0, stream>>>(tok_w1, offs, w1ct);
    k_tok1<<<dim3(16, 16), dim3(1024), 0, stream>>>(x, ln1_g, ln1_b, w1ct, P);
    k_tok1_fin<<<dim3(512), dim3(256), 0, stream>>>(P, tok_b1, g1b);
    k_tok2mlp<<<dim3(64, 16), dim3(512), 0, stream>>>(g1b, w2t, tok_b2, ln2_g, ln2_b,
                                                      w1p, w2p, ch_b1, ch_b2, out);
}